// Round 1
// 240.121 us; speedup vs baseline: 1.1450x; 1.1450x over previous
//
#include <hip/hip_runtime.h>

// Problem constants (ConvHex): B=256, C_IN=64, C_OUT=128, H=1039, K=6
// Dtypes: x, weights, bias, out = fp32; neighbors = int32.
// Compute uses bf16 MFMA; threshold 3.375e-2 covers bf16 rounding (measured 7.8e-3).
#define BATCH 256
#define CIN   64
#define COUT  128
#define HEX   1039
#define KNB   6
#define KDIM  448          // CIN * (KNB + 1)
#define BN    64           // h per block in GEMM
#define NTH   17           // ceil(HEX / BN)  (GEMM tiling)
#define CPX   544          // (BATCH*NTH)/8 blocks per XCD (bijective swizzle)
#define THT   32           // h per transpose block
#define NTT   33           // ceil(HEX / THT)
#define TBLK  (BATCH * NTT)   // 8448 transpose blocks
#define HROWS (HEX + 1)    // xt rows per batch: +1 zero row at index HEX

typedef __attribute__((ext_vector_type(8))) short bf16x8;   // 8 bf16 = 4 VGPRs
typedef __attribute__((ext_vector_type(4))) float f32x4;

__device__ __forceinline__ unsigned short f2bf(float f) {
    unsigned int u = __builtin_bit_cast(unsigned int, f);
    u += 0x7fffu + ((u >> 16) & 1);          // RTNE
    return (unsigned short)(u >> 16);
}

// ---------------------------------------------------------------------------
// Kernel 1 (merged): blocks [0, TBLK) transpose x[b][c][h] fp32 -> xt[b][h][c]
// bf16; blocks [TBLK, TBLK+260) do the prep work (wf pack / invtv / gidx /
// zero row). Prep is independent of the transpose and hides in its tail.
__global__ __launch_bounds__(256) void k_pre(const float* __restrict__ x,
                                             const float* __restrict__ wc,
                                             const float* __restrict__ wn,
                                             const int* __restrict__ nb,
                                             unsigned short* __restrict__ xt,
                                             unsigned short* __restrict__ wf,
                                             float* __restrict__ invtv,
                                             int* __restrict__ gidx) {
    int bid = blockIdx.x;
    int tid = threadIdx.x;
    if (bid < TBLK) {
        // ---- transpose: 8 strided 4B loads/thread (block-local 8KB -> L1),
        // wave writes 8 contiguous 128B bf16 rows, fully coalesced 16B/lane.
        int b  = bid / NTT;
        int ht = bid % NTT;
        int h  = ht * THT + (tid >> 3);
        int c8 = (tid & 7) * 8;
        if (h >= HEX) return;
        const float* xb = x + (size_t)b * (CIN * HEX) + h;
        bf16x8 v;
        #pragma unroll
        for (int k = 0; k < 8; ++k)
            v[k] = (short)f2bf(xb[(size_t)(c8 + k) * HEX]);
        *(bf16x8*)(xt + (size_t)b * (HROWS * CIN) + (size_t)h * CIN + c8) = v;
        return;
    }
    int blk = bid - TBLK;
    if (blk < 224) {
        // wf element e = ((kb*8 + mt)*64 + lane)*8 + j :
        //   o = mt*16 + (lane&15); kd = kb*32 + (lane>>4)*8 + j = jn*64 + c
        int e    = blk * 256 + tid;              // 0 .. 57343
        int j    = e & 7;
        int lane = (e >> 3) & 63;
        int mt   = (e >> 9) & 7;
        int kb   = e >> 12;                      // 0..13
        int o  = mt * 16 + (lane & 15);
        int kd = kb * 32 + (lane >> 4) * 8 + j;
        int jn = kd >> 6;
        int c  = kd & 63;
        float v = (jn == 0) ? wc[o * CIN + c]
                            : wn[(o * CIN + c) * KNB + (jn - 1)];
        wf[e] = f2bf(v);
    } else if (blk < 229) {
        int h = (blk - 224) * 256 + tid;
        if (h < HEX) {
            int cnt = 1;
            #pragma unroll
            for (int k = 0; k < KNB; ++k) cnt += (nb[h * KNB + k] >= 0) ? 1 : 0;
            invtv[h] = 1.0f / (float)cnt;
        }
    } else if (blk < 259) {
        int e = (blk - 229) * 256 + tid;
        if (e < NTH * KDIM) {
            int ht = e / KDIM;
            int p  = e - ht * KDIM;
            int jn = p >> 6;
            int n  = p & 63;
            int h  = ht * 64 + n;
            int g  = HEX;                        // zero row
            if (h < HEX) {
                if (jn == 0) g = h;
                else {
                    int t = nb[h * KNB + (jn - 1)];
                    if (t >= 0) g = t;
                }
            }
            gidx[e] = g;
        }
    } else {
        // zero row per batch: xt[b][HEX][0..63] = 0   (256 b x 128 B)
        int b = tid;                             // 256 threads = 256 batches
        bf16x8 z = {};
        unsigned short* row = xt + (size_t)b * (HROWS * CIN) + (size_t)HEX * CIN;
        #pragma unroll
        for (int k = 0; k < 8; ++k)
            *(bf16x8*)(row + k * 8) = z;
    }
}

// ---------------------------------------------------------------------------
// Kernel 2: gathered GEMM. Block = (b, 64-h tile); 8 waves (512 thr).
// Wave grid = 4m x 2n: wave wv computes o in [ (wv&3)*32, +32 ) x 32 h
// (nh = wv>>2 selects the h half). Per k-step: 2 A-frags (global, 2-deep
// prefetch), 2 B-frags (LDS), 4 MFMA -> each B b128 feeds 2 MFMAs, halving
// LDS reads vs the 8m x 1n layout (224 vs 448 b128/block).
// Bs is dense [448 rows][128B] with per-row XOR chunk swizzle (chunk ^= row&7):
// both ds_write and ds_read stay perfectly bank-balanced (8 lanes/slot).
// Grid is XCD-swizzled (4352 = 8*544, bijective) so all 17 tiles of a batch
// share one XCD's L2 for xt[b].
__global__ __launch_bounds__(512, 4) void k_gemm(const unsigned short* __restrict__ xt,
                                                 const unsigned short* __restrict__ wf,
                                                 const int* __restrict__ gidx,
                                                 const float* __restrict__ invtv,
                                                 const float* __restrict__ bias,
                                                 float* __restrict__ out) {
    __shared__ __align__(16) unsigned short Bs[KDIM * CIN];   // 57344 B -> 2 blocks/CU

    int bid = blockIdx.x;
    int id2 = (bid & 7) * CPX + (bid >> 3);   // XCD-contiguous batch ranges
    int b   = id2 / NTH;
    int ht  = id2 - b * NTH;
    int h0  = ht * BN;
    int tid = threadIdx.x;
    int lane = tid & 63;
    int wv   = tid >> 6;                      // 0..7

    // ---- stage B: row p = jn*64+n  ->  Bs[p][chunk ^ (p&7)] (branch-free)
    {
        const unsigned short* xtb = xt + (size_t)b * (HROWS * CIN);
        const int* gt = gidx + ht * KDIM;
        int r8 = lane >> 3;                  // row within 8-row octet (= p&7)
        int cc = lane & 7;                   // 16B chunk within the 128B row
        int gs[7];
        #pragma unroll
        for (int i = 0; i < 7; ++i)          // issue all 7 index loads first
            gs[i] = gt[(wv * 7 + i) * 8 + r8];
        #pragma unroll
        for (int i = 0; i < 7; ++i) {
            int t = wv * 7 + i;              // octet 0..55
            bf16x8 v = *(const bf16x8*)(xtb + (size_t)gs[i] * CIN + (cc << 3));
            *(bf16x8*)(Bs + t * 512 + r8 * 64 + ((cc ^ r8) << 3)) = v;
        }
    }
    __syncthreads();

    int quad = lane >> 4;
    int l16  = lane & 15;
    int m    = wv & 3;                       // m-pair: o-tiles {2m, 2m+1}
    int nh   = wv >> 2;                      // h half 0..1
    int swz  = l16 & 7;                      // row&7 of every B row this lane reads

    f32x4 acc[2][2] = {};                    // [mi][nt]

    const bf16x8* wfv = (const bf16x8*)wf;
    const char*   BsB = (const char*)Bs;

    bf16x8 a0[2], a1[2], a2[2];
    #pragma unroll
    for (int mi = 0; mi < 2; ++mi) {         // 2-deep A prefetch pipeline
        a0[mi] = wfv[(0 * 8 + 2 * m + mi) * 64 + lane];
        a1[mi] = wfv[(1 * 8 + 2 * m + mi) * 64 + lane];
    }

    #pragma unroll
    for (int ks = 0; ks < 14; ++ks) {
        if (ks < 12) {
            #pragma unroll
            for (int mi = 0; mi < 2; ++mi)
                a2[mi] = wfv[((ks + 2) * 8 + 2 * m + mi) * 64 + lane];
        }
        int jn    = ks >> 1;
        int chunk = (((ks & 1) << 2) + quad) ^ swz;
        #pragma unroll
        for (int nt = 0; nt < 2; ++nt) {
            int n = nh * 32 + nt * 16 + l16;
            bf16x8 bb = *(const bf16x8*)(BsB + (((jn << 6) + n) << 7) + (chunk << 4));
            acc[0][nt] = __builtin_amdgcn_mfma_f32_16x16x32_bf16(a0[0], bb, acc[0][nt], 0, 0, 0);
            acc[1][nt] = __builtin_amdgcn_mfma_f32_16x16x32_bf16(a0[1], bb, acc[1][nt], 0, 0, 0);
        }
        a0[0] = a1[0]; a0[1] = a1[1];
        a1[0] = a2[0]; a1[1] = a2[1];
    }

    // ---- epilogue: D col = l16 (h), row = quad*4 + r (o within 16-tile)
    float* outb = out + (size_t)b * ((size_t)COUT * HEX);
    #pragma unroll
    for (int nt = 0; nt < 2; ++nt) {
        int h = h0 + nh * 32 + nt * 16 + l16;
        if (h >= HEX) continue;
        float s = invtv[h];
        #pragma unroll
        for (int mi = 0; mi < 2; ++mi) {
            #pragma unroll
            for (int r = 0; r < 4; ++r) {
                int o = (2 * m + mi) * 16 + quad * 4 + r;
                outb[(size_t)o * HEX + h] = acc[mi][nt][r] * s + bias[o];
            }
        }
    }
}

// ---------------------------------------------------------------------------
extern "C" void kernel_launch(void* const* d_in, const int* in_sizes, int n_in,
                              void* d_out, int out_size, void* d_ws, size_t ws_size,
                              hipStream_t stream) {
    const float* x    = (const float*)d_in[0];   // [256][64][1039] fp32
    const int*   nb   = (const int*)d_in[1];     // [1039][6] int32
    const float* wc   = (const float*)d_in[2];   // [128][64] fp32
    const float* wn   = (const float*)d_in[3];   // [128][64][6] fp32
    const float* bias = (const float*)d_in[4];   // [128] fp32
    float*       out  = (float*)d_out;           // [256][128][1039] fp32

    // workspace layout (we use ~34.3 MB of the harness workspace)
    const size_t INVTV_OFF = (size_t)KDIM * COUT * 2;        // 114688
    const size_t GIDX_OFF  = 131072;                         // 17*448*4 = 30464 B
    const size_t XT_OFF    = 196608;                         // 16B-aligned
    unsigned short* wf    = (unsigned short*)d_ws;
    float*          invtv = (float*)((char*)d_ws + INVTV_OFF);
    int*            gidx  = (int*)((char*)d_ws + GIDX_OFF);
    unsigned short* xt    = (unsigned short*)((char*)d_ws + XT_OFF);

    hipLaunchKernelGGL(k_pre,  dim3(TBLK + 260), dim3(256), 0, stream,
                       x, wc, wn, nb, xt, wf, invtv, gidx);
    hipLaunchKernelGGL(k_gemm, dim3(BATCH * NTH), dim3(512), 0, stream,
                       xt, wf, gidx, invtv, bias, out);
}

// Round 2
// 227.961 us; speedup vs baseline: 1.2061x; 1.0533x over previous
//
#include <hip/hip_runtime.h>

// Problem constants (ConvHex): B=256, C_IN=64, C_OUT=128, H=1039, K=6
// Dtypes: x, weights, bias, out = fp32; neighbors = int32.
// Compute uses bf16 MFMA; threshold 3.375e-2 covers bf16 rounding (measured 7.8e-3).
//
// Design (round 2): one block per batch. x[b] is transposed straight into LDS
// (bf16, XOR-swizzled 128B rows, 1040 rows = 130 KB), then all 17 h-tiles are
// computed from LDS in place via gathered ds_read_b128 (neighbors are batch-
// local). No xt global round-trip, no staging copy, no per-tile barrier.
// A-fragments (wf) live entirely in registers (112 VGPR), loaded once.
#define BATCH 256
#define CIN   64
#define COUT  128
#define HEX   1039
#define KNB   6
#define ZROW  HEX              // zero row index in LDS (gather target for pads)
#define NTH   17               // ceil(HEX / 64) h-tiles
#define LDSB  ((HEX + 1) * 128)   // 1040 rows * 128 B = 133120 B

typedef __attribute__((ext_vector_type(8))) short bf16x8;   // 8 bf16 = 4 VGPRs
typedef __attribute__((ext_vector_type(4))) float f32x4;

__device__ __forceinline__ unsigned short f2bf(float f) {
    unsigned int u = __builtin_bit_cast(unsigned int, f);
    u += 0x7fffu + ((u >> 16) & 1);          // RTNE
    return (unsigned short)(u >> 16);
}

// ---------------------------------------------------------------------------
// k_prep: pack [Wc|Wn] fp32 -> wf bf16 in MFMA A-fragment lane order.
// wf element e = ((kb*8 + mt)*64 + lane)*8 + j :
//   o = mt*16 + (lane&15); kd = kb*32 + (lane>>4)*8 + j = jn*64 + c
__global__ __launch_bounds__(256) void k_prep(const float* __restrict__ wc,
                                              const float* __restrict__ wn,
                                              unsigned short* __restrict__ wf) {
    int e    = blockIdx.x * 256 + threadIdx.x;   // 0 .. 57343
    int j    = e & 7;
    int lane = (e >> 3) & 63;
    int mt   = (e >> 9) & 7;
    int kb   = e >> 12;                          // 0..13
    int o  = mt * 16 + (lane & 15);
    int kd = kb * 32 + (lane >> 4) * 8 + j;
    int jn = kd >> 6;
    int c  = kd & 63;
    float v = (jn == 0) ? wc[o * CIN + c]
                        : wn[(o * CIN + c) * KNB + (jn - 1)];
    wf[e] = f2bf(v);
}

// ---------------------------------------------------------------------------
// k_main: block = batch. 512 threads = 8 waves (4 m-pairs x 2 h-halves).
// Phase 1: transpose x[b][c][h] -> LDS row h (64 bf16, swizzled chunks).
//   Row layout: byte(h, chunk q) = h*128 + ((q ^ (h&7))<<4). Rows are 128B =
//   exactly 32 banks, so the bank pattern depends only on the chunk slot; the
//   XOR keeps both the phase-1 b128 writes (8h x 8q per wave: bijective) and
//   the phase-2 gathered b128 reads (random rows -> near-uniform slots)
//   bank-balanced.
// Phase 2: per tile ht, wave (m,nh) computes o in [32m,32m+32) x 32 h.
//   B-frags gathered from LDS by per-lane row index (center / nb / ZROW);
//   A entirely in registers; 56 MFMA per wave per tile; no barriers.
__global__ __launch_bounds__(512, 2) void k_main(const float* __restrict__ x,
                                                 const int* __restrict__ nb,
                                                 const unsigned short* __restrict__ wf,
                                                 const float* __restrict__ bias,
                                                 float* __restrict__ out) {
    extern __shared__ __align__(16) unsigned short XT[];   // [1040 rows][128 B]

    int b    = blockIdx.x;
    int tid  = threadIdx.x;
    int lane = tid & 63;
    int wv   = tid >> 6;
    int quad = lane >> 4;
    int l16  = lane & 15;
    int m    = wv & 3;                   // m-pair: o-tiles {2m, 2m+1}
    int nh   = wv >> 2;                  // h half 0..1

    // ---- A fragments: 28 frags = 112 VGPR, loaded once (issue early).
    const bf16x8* wfv = (const bf16x8*)wf;
    bf16x8 A[14][2];
    #pragma unroll
    for (int kb = 0; kb < 14; ++kb)
        #pragma unroll
        for (int mi = 0; mi < 2; ++mi)
            A[kb][mi] = wfv[(kb * 8 + 2 * m + mi) * 64 + lane];

    float bs[2][4];
    #pragma unroll
    for (int mi = 0; mi < 2; ++mi)
        #pragma unroll
        for (int r = 0; r < 4; ++r)
            bs[mi][r] = bias[(2 * m + mi) * 16 + quad * 4 + r];

    // ---- phase 1: transpose into LDS. Task e = h*8 + cc (1040*8 = 8320).
    // Per task: 8 strided 4B loads (wave: 8 c-rows x 32B segments, each line
    // consumed once) -> one swizzled b128 LDS write (conflict-free).
    {
        const float* xb = x + (size_t)b * (CIN * HEX);
        for (int t = 0; t < 9; ++t) {
            #pragma unroll
            for (int u = 0; u < 2; ++u) {       // 2 tasks in flight per iter
                int e = t * 1024 + u * 512 + tid;
                if (e < 8320) {
                    int h  = e >> 3;
                    int cc = e & 7;
                    bf16x8 v = {};
                    if (h < HEX) {
                        #pragma unroll
                        for (int k = 0; k < 8; ++k)
                            v[k] = (short)f2bf(xb[(size_t)(cc * 8 + k) * HEX + h]);
                    }
                    *(bf16x8*)((char*)XT + h * 128 + ((cc ^ (h & 7)) << 4)) = v;
                }
            }
        }
    }
    __syncthreads();

    // ---- phase 2: 17 tiles, no barriers.
    int ho = nh * 32 + l16;                  // h = ht*64 + ho + nt*16
    int rawn[2][6];                          // next tile's nb values
    int voff[2][7];                          // current tile's LDS byte offsets
    float inv[2];

    auto loadraw = [&](int ht2) {            // issue 12 nb loads for tile ht2
        #pragma unroll
        for (int nt = 0; nt < 2; ++nt) {
            int h  = ht2 * 64 + ho + nt * 16;
            int hs = (h < HEX) ? h : 0;
            #pragma unroll
            for (int j = 0; j < KNB; ++j)
                rawn[nt][j] = nb[hs * KNB + j];
        }
    };
    // byte offset of (row g, chunk quad) with swizzle; ks-odd XORs bit 6.
    auto offg = [&](int g) { return (g << 7) | ((quad ^ (g & 7)) << 4); };

    loadraw(0);
    float* outb = out + (size_t)b * ((size_t)COUT * HEX);

    for (int ht = 0; ht < NTH; ++ht) {
        // finalize current tile from rawn (VALU only)
        #pragma unroll
        for (int nt = 0; nt < 2; ++nt) {
            int h = ht * 64 + ho + nt * 16;
            bool hv = (h < HEX);
            voff[nt][0] = offg(hv ? h : ZROW);
            int cnt = 1;
            #pragma unroll
            for (int j = 0; j < KNB; ++j) {
                int t2 = rawn[nt][j];
                bool val = hv && (t2 >= 0);
                cnt += val ? 1 : 0;
                voff[nt][j + 1] = offg(val ? t2 : ZROW);
            }
            inv[nt] = 1.0f / (float)cnt;
        }
        if (ht + 1 < NTH) loadraw(ht + 1);   // prefetch next tile's indices

        f32x4 acc[2][2] = {};                // [mi][nt]
        #pragma unroll
        for (int ks = 0; ks < 14; ++ks) {
            int jn = ks >> 1;
            int xr = (ks & 1) << 6;          // odd ks: chunk slot +4 (XOR bit 6)
            #pragma unroll
            for (int nt = 0; nt < 2; ++nt) {
                bf16x8 bb = *(const bf16x8*)((const char*)XT + (voff[nt][jn] ^ xr));
                acc[0][nt] = __builtin_amdgcn_mfma_f32_16x16x32_bf16(A[ks][0], bb, acc[0][nt], 0, 0, 0);
                acc[1][nt] = __builtin_amdgcn_mfma_f32_16x16x32_bf16(A[ks][1], bb, acc[1][nt], 0, 0, 0);
            }
        }

        // epilogue: D col = l16 (h), row = quad*4 + r (o within 16-tile)
        #pragma unroll
        for (int nt = 0; nt < 2; ++nt) {
            int h = ht * 64 + ho + nt * 16;
            if (h >= HEX) continue;
            float s = inv[nt];
            #pragma unroll
            for (int mi = 0; mi < 2; ++mi)
                #pragma unroll
                for (int r = 0; r < 4; ++r) {
                    int o = (2 * m + mi) * 16 + quad * 4 + r;
                    outb[(size_t)o * HEX + h] = acc[mi][nt][r] * s + bs[mi][r];
                }
        }
    }
}

// ---------------------------------------------------------------------------
extern "C" void kernel_launch(void* const* d_in, const int* in_sizes, int n_in,
                              void* d_out, int out_size, void* d_ws, size_t ws_size,
                              hipStream_t stream) {
    const float* x    = (const float*)d_in[0];   // [256][64][1039] fp32
    const int*   nb   = (const int*)d_in[1];     // [1039][6] int32
    const float* wc   = (const float*)d_in[2];   // [128][64] fp32
    const float* wn   = (const float*)d_in[3];   // [128][64][6] fp32
    const float* bias = (const float*)d_in[4];   // [128] fp32
    float*       out  = (float*)d_out;           // [256][128][1039] fp32

    unsigned short* wf = (unsigned short*)d_ws;  // 114688 B of workspace

    static bool s_attr_done = false;
    if (!s_attr_done) {                          // host-side, graph-safe, once
        hipFuncSetAttribute((const void*)k_main,
                            hipFuncAttributeMaxDynamicSharedMemorySize, LDSB);
        s_attr_done = true;
    }

    hipLaunchKernelGGL(k_prep, dim3(224),   dim3(256), 0,    stream, wc, wn, wf);
    hipLaunchKernelGGL(k_main, dim3(BATCH), dim3(512), LDSB, stream,
                       x, nb, wf, bias, out);
}